// Round 10
// baseline (29.677 us; speedup 1.0000x reference)
//
#include <hip/hip_runtime.h>
#include <math.h>

// Fuzzyfier: out[b,v,s,p] = mv >= 0.1 ? mv : 0,  mv = exp(-(x-c)^2 / (2 s^2))
// x (64,8,1024) f32, fuzzy_sets (8,64,2) f32 [c, sigma]. Out 134 MB f32.
// Write ceiling (measured fillBuffer, 512 MiB): 6.6-6.9 TB/s.
//
// R5/R8/R9 all plateau at 27.6-27.8 us (4.86 TB/s) across three different
// structures -> not VALU (est. 5-6 us), not occupancy (R9 pinned 8 w/EU),
// not per-instruction contiguity (1 KiB solid per store instr). Shared
// factor: cached stores streaming 134 MB through L2 (write-allocate +
// dirty-evict). R10 = R9 + nontemporal on the two contiguous stores ONLY
// (R7's nt regression was confounded by a strided mapping; here lines are
// fully covered by one instruction, no partial-line WC risk).
//
// Alpha-cut decision: f64 replay of the argument chain, threshold in log
// space (exp(td)>=0.1 <=> td>=ln 0.1); window ~2 ulp_f64, prob ~1e-8.
// Kept value = fast-path f32 (err ~1e-4 << bf16-level 2e-2 tolerance).

#define LOG2E    1.4426950408889634f
#define LOG2_CUT -3.321928094887362f     // log2(0.1), f32
#define BAND2    2e-3f
#define LN01_D   -2.302585092994045684   // ln(0.1), nearest double

typedef float f32x4 __attribute__((ext_vector_type(4)));

#if __has_builtin(__builtin_amdgcn_exp2f)
#define FAST_EXP2(x) __builtin_amdgcn_exp2f(x)
#else
#define FAST_EXP2(x) exp2f(x)
#endif

__global__ __launch_bounds__(256, 8) void fuzzyfier_kernel(
    const float* __restrict__ x,     // B*V*S
    const float* __restrict__ fs,    // V*P*2 interleaved (c, sigma)
    float* __restrict__ out,         // B*V*S*P
    int totalPair)                   // (B*V*S*P)/8 row-pair chunks
{
    int idx    = blockIdx.x * 256 + threadIdx.x;
    int stride = gridDim.x * 256;    // 524288 -> (v,q) invariant per thread

    int q4 = (idx & 15) << 2;                    // p base (invariant)
    int j0 = idx >> 4;
    int rA0 = ((j0 >> 2) << 3) + (j0 & 3);
    int v   = (rA0 >> 10) & 7;                   // invariant across stride
    int pb  = (v << 6) + q4;

    float c[4], w[4], sg[4];
    #pragma unroll
    for (int k = 0; k < 4; ++k) {
        float2 cs = reinterpret_cast<const float2*>(fs)[pb + k];  // 4 KB, hot
        c[k]  = cs.x;
        sg[k] = cs.y;
        w[k]  = -LOG2E / (2.0f * (cs.y * cs.y));   // one-time precise div
    }

    f32x4* o4 = reinterpret_cast<f32x4*>(out);

    for (int i = idx; i < totalPair; i += stride) {
        int jj   = i >> 4;
        int q    = i & 15;
        int rowA = ((jj >> 2) << 3) + (jj & 3);
        int rowB = rowA + 4;                 // same v (8-row block, 8 | 1024)
        float xa = x[rowA];                  // 16 lanes share -> L1 broadcast
        float xb = x[rowB];

        float oa[4], ob[4];
        #pragma unroll
        for (int k = 0; k < 4; ++k) {
            float da = xa - c[k];
            float ua = (da * da) * w[k];         // = log2(mv)
            float ma = FAST_EXP2(ua);
            oa[k] = (ma >= 0.1f) ? ma : 0.0f;
            if (__builtin_expect(fabsf(ua - LOG2_CUT) < BAND2, 0)) {
                double dd = (double)xa - (double)c[k];
                double sd = (double)sg[k];
                double td = -(dd * dd) / (2.0 * (sd * sd));
                oa[k] = (td >= LN01_D) ? ma : 0.0f;
            }
            float db = xb - c[k];
            float ub = (db * db) * w[k];
            float mb = FAST_EXP2(ub);
            ob[k] = (mb >= 0.1f) ? mb : 0.0f;
            if (__builtin_expect(fabsf(ub - LOG2_CUT) < BAND2, 0)) {
                double dd = (double)xb - (double)c[k];
                double sd = (double)sg[k];
                double td = -(dd * dd) / (2.0 * (sd * sd));
                ob[k] = (td >= LN01_D) ? mb : 0.0f;
            }
        }

        // Each store instruction: wave-contiguous 1 KiB, nontemporal.
        f32x4 va = { oa[0], oa[1], oa[2], oa[3] };
        f32x4 vb = { ob[0], ob[1], ob[2], ob[3] };
        __builtin_nontemporal_store(va, &o4[rowA * 16 + q]);
        __builtin_nontemporal_store(vb, &o4[rowB * 16 + q]);
    }
}

extern "C" void kernel_launch(void* const* d_in, const int* in_sizes, int n_in,
                              void* d_out, int out_size, void* d_ws, size_t ws_size,
                              hipStream_t stream) {
    const float* x  = (const float*)d_in[0];
    const float* fs = (const float*)d_in[1];
    float* out      = (float*)d_out;

    int totalPair = out_size / 8;   // 4,194,304 (exactly 8 iters/thread)

    const int block = 256;
    const int grid  = 2048;         // keep ==0 mod 512 for (v,q) invariance

    hipLaunchKernelGGL(fuzzyfier_kernel, dim3(grid), dim3(block), 0, stream,
                       x, fs, out, totalPair);
}

// Round 11
// 27.383 us; speedup vs baseline: 1.0838x; 1.0838x over previous
//
#include <hip/hip_runtime.h>
#include <math.h>

// Fuzzyfier: out[b,v,s,p] = mv >= 0.1 ? mv : 0,  mv = exp(-(x-c)^2 / (2 s^2))
// x (64,8,1024) f32, fuzzy_sets (8,64,2) f32 [c, sigma]. Out 134 MB f32.
//
// FINAL (R9 restored; R10's nontemporal stores regressed +2 us).
// Roofline accounting: t = c + bytes/BW fit over {ours 27.6us/134MB,
// fillBuffer ~80us/537MB} gives BW ~7.7 TB/s steady-state + c ~10 us fixed
// launch overhead (documented harness constant). Streaming phase is at the
// achievable write-BW ceiling; structure (R5/R8/R9), occupancy (8 w/EU),
// ILP (2x), and nt stores were all explored and neutral/negative.
//
// Numerics: fast path mv = exp2((d*d) * (-log2e/(2 s^2))) — 6 VALU ops,
// value error ~1e-4 << bf16-level 2e-2 tolerance. Alpha-cut decision
// protected by rare f64 replay of numpy's argument chain, decided in log
// space (exp(td)>=0.1 <=> td>=ln 0.1; disagreement window ~2 ulp_f64).
// Store mapping: lane -> (row, 4p); each store instruction is a solid,
// wave-contiguous 1 KiB (R7 lesson: per-instruction contiguity).

#define LOG2E    1.4426950408889634f
#define LOG2_CUT -3.321928094887362f     // log2(0.1), f32
#define BAND2    2e-3f
#define LN01_D   -2.302585092994045684   // ln(0.1), nearest double

#if __has_builtin(__builtin_amdgcn_exp2f)
#define FAST_EXP2(x) __builtin_amdgcn_exp2f(x)
#else
#define FAST_EXP2(x) exp2f(x)
#endif

__global__ __launch_bounds__(256, 8) void fuzzyfier_kernel(
    const float* __restrict__ x,     // B*V*S
    const float* __restrict__ fs,    // V*P*2 interleaved (c, sigma)
    float* __restrict__ out,         // B*V*S*P
    int totalPair)                   // (B*V*S*P)/8 row-pair chunks
{
    int idx    = blockIdx.x * 256 + threadIdx.x;
    int stride = gridDim.x * 256;    // 524288 -> (v,q) invariant per thread

    int q4 = (idx & 15) << 2;                    // p base (invariant)
    int j0 = idx >> 4;
    int rA0 = ((j0 >> 2) << 3) + (j0 & 3);
    int v   = (rA0 >> 10) & 7;                   // invariant across stride
    int pb  = (v << 6) + q4;

    float c[4], w[4], sg[4];
    #pragma unroll
    for (int k = 0; k < 4; ++k) {
        float2 cs = reinterpret_cast<const float2*>(fs)[pb + k];  // 4 KB, hot
        c[k]  = cs.x;
        sg[k] = cs.y;
        w[k]  = -LOG2E / (2.0f * (cs.y * cs.y));   // one-time precise div
    }

    float4* o4 = reinterpret_cast<float4*>(out);

    for (int i = idx; i < totalPair; i += stride) {
        int jj   = i >> 4;
        int q    = i & 15;
        int rowA = ((jj >> 2) << 3) + (jj & 3);
        int rowB = rowA + 4;                 // same v (8-row block, 8 | 1024)
        float xa = x[rowA];                  // 16 lanes share -> L1 broadcast
        float xb = x[rowB];

        float oa[4], ob[4];
        #pragma unroll
        for (int k = 0; k < 4; ++k) {
            float da = xa - c[k];
            float ua = (da * da) * w[k];         // = log2(mv)
            float ma = FAST_EXP2(ua);
            oa[k] = (ma >= 0.1f) ? ma : 0.0f;
            if (__builtin_expect(fabsf(ua - LOG2_CUT) < BAND2, 0)) {
                // decision-only f64 replay of numpy's argument chain
                double dd = (double)xa - (double)c[k];
                double sd = (double)sg[k];
                double td = -(dd * dd) / (2.0 * (sd * sd));
                oa[k] = (td >= LN01_D) ? ma : 0.0f;
            }
            float db = xb - c[k];
            float ub = (db * db) * w[k];
            float mb = FAST_EXP2(ub);
            ob[k] = (mb >= 0.1f) ? mb : 0.0f;
            if (__builtin_expect(fabsf(ub - LOG2_CUT) < BAND2, 0)) {
                double dd = (double)xb - (double)c[k];
                double sd = (double)sg[k];
                double td = -(dd * dd) / (2.0 * (sd * sd));
                ob[k] = (td >= LN01_D) ? mb : 0.0f;
            }
        }

        // Each store instruction: wave writes 1 KiB contiguous.
        o4[rowA * 16 + q] = make_float4(oa[0], oa[1], oa[2], oa[3]);
        o4[rowB * 16 + q] = make_float4(ob[0], ob[1], ob[2], ob[3]);
    }
}

extern "C" void kernel_launch(void* const* d_in, const int* in_sizes, int n_in,
                              void* d_out, int out_size, void* d_ws, size_t ws_size,
                              hipStream_t stream) {
    const float* x  = (const float*)d_in[0];
    const float* fs = (const float*)d_in[1];
    float* out      = (float*)d_out;

    int totalPair = out_size / 8;   // 4,194,304 (exactly 8 iters/thread)

    const int block = 256;
    const int grid  = 2048;         // keep ==0 mod 512 for (v,q) invariance

    hipLaunchKernelGGL(fuzzyfier_kernel, dim3(grid), dim3(block), 0, stream,
                       x, fs, out, totalPair);
}